// Round 8
// baseline (117.120 us; speedup 1.0000x reference)
//
#include <hip/hip_runtime.h>
#include <hip/hip_bf16.h>

#define S_LEN 2048
#define D_K   64
#define N_H   16
#define N_B   4
#define KVB   64
#define NT    (S_LEN / KVB)
#define QPB   128                 // q-rows per block (4 waves x 32)
#define NQB   (S_LEN / QPB)       // 16
#define WS_NEED (2L * N_B * N_H * S_LEN * D_K * (long)sizeof(short))

typedef __attribute__((ext_vector_type(8)))  short bf16x8;
typedef __attribute__((ext_vector_type(16))) float f32x16;
typedef unsigned int u32;
typedef unsigned short u16;
typedef __attribute__((ext_vector_type(4))) u32 u32x4;

__device__ inline short f2bfs(float x) {
    __hip_bfloat16 h = __float2bfloat16(x);
    return __builtin_bit_cast(short, h);
}

__device__ inline bf16x8 cvt8(const float* __restrict__ p) {
    float4 a = *(const float4*)p;
    float4 b = *(const float4*)(p + 4);
    bf16x8 f;
    f[0] = f2bfs(a.x); f[1] = f2bfs(a.y);
    f[2] = f2bfs(a.z); f[3] = f2bfs(a.w);
    f[4] = f2bfs(b.x); f[5] = f2bfs(b.y);
    f[6] = f2bfs(b.z); f[7] = f2bfs(b.w);
    return f;
}

__device__ inline bf16x8 cvt8s(const float* __restrict__ p, float s) {
    float4 a = *(const float4*)p;
    float4 b = *(const float4*)(p + 4);
    bf16x8 f;
    f[0] = f2bfs(a.x * s); f[1] = f2bfs(a.y * s);
    f[2] = f2bfs(a.z * s); f[3] = f2bfs(a.w * s);
    f[4] = f2bfs(b.x * s); f[5] = f2bfs(b.y * s);
    f[6] = f2bfs(b.z * s); f[7] = f2bfs(b.w * s);
    return f;
}

// bf16 (packed pair) -> f32 expansion: bf16 is the top half of f32
__device__ inline float blo(u32 u) { return __builtin_bit_cast(float, u << 16); }
__device__ inline float bhi(u32 u) { return __builtin_bit_cast(float, u & 0xffff0000u); }

// V^T swizzle: spreads row-d b128 reads across banks
__device__ inline int vswz(int d) { return ((d & 7) ^ ((d >> 3) & 7)) << 4; }

__device__ inline void gld16(const void* g, void* l) {
    __builtin_amdgcn_global_load_lds(
        (const __attribute__((address_space(1))) void*)g,
        (__attribute__((address_space(3))) void*)l, 16, 0, 0);
}

// ---------------- pre-pass: K -> bf16 linear, V -> bf16 transposed ----------------
__global__ __launch_bounds__(256)
void cvt_kv(const float* __restrict__ k, const float* __restrict__ v,
            short* __restrict__ kbf, short* __restrict__ vt) {
    const int t = threadIdx.x;
    {
        long i = ((long)blockIdx.x * 256 + t) * 16;
        bf16x8 f0 = cvt8(k + i), f1 = cvt8(k + i + 8);
        *(bf16x8*)(kbf + i)     = f0;
        *(bf16x8*)(kbf + i + 8) = f1;
    }
    __shared__ __align__(16) short tile[64][72];
    const int bh = blockIdx.x >> 5, s0 = (blockIdx.x & 31) * 64;
    const int r = t >> 2, c0 = (t & 3) * 16;
    const float* src = v + ((long)bh * S_LEN + s0 + r) * D_K + c0;
    bf16x8 f0 = cvt8(src), f1 = cvt8(src + 8);
    *(bf16x8*)&tile[r][c0]     = f0;
    *(bf16x8*)&tile[r][c0 + 8] = f1;
    __syncthreads();
    const int dd = t >> 2, k0 = (t & 3) * 16;
    bf16x8 g0, g1;
#pragma unroll
    for (int j = 0; j < 8; ++j) {
        g0[j] = tile[k0 + j][dd];
        g1[j] = tile[k0 + 8 + j][dd];
    }
    short* dst = vt + ((long)bh * D_K + dd) * S_LEN + s0 + k0;
    *(bf16x8*)dst       = g0;
    *(bf16x8*)(dst + 8) = g1;
}

// ---------------- main attention kernel (bf16 K / V^T from ws) ----------------
__global__ __launch_bounds__(256)
void attn_fwd(const float* __restrict__ q, const short* __restrict__ kbf,
              const short* __restrict__ vtb, const int* __restrict__ mask,
              float* __restrict__ out) {
    // XCD-aware bijective swizzle (1024 = 8*128)
    const int id      = blockIdx.x;
    const int logical = (id & 7) * 128 + (id >> 3);
    const int bh      = logical >> 4;
    const int qblk    = logical & 15;
    const int b       = bh >> 4;
    const int t       = threadIdx.x;
    const int lane    = t & 63;
    const int wq      = t >> 6;
    const int hb      = lane >> 5;
    const int ql      = lane & 31;

    // LDS = 16K (K) + 16K (V) + 4K (bias bf16) = 36 KB -> 4 blocks/CU resident
    __shared__ __align__(16) short kbuf[2][KVB * D_K];   // [key][d], XOR (row&7)<<4
    __shared__ __align__(16) short vbuf[2][D_K * KVB];   // [d][key], XOR vswz(d)
    __shared__ __align__(8)  u16   mbias[S_LEN];         // bf16: 0 or -inf

    const float scale2 = 0.125f * 1.44269504f;           // 1/sqrt(64)*log2(e)
    const long  baseq  = (long)bh * S_LEN * D_K;
    const int   qrow0  = qblk * QPB + wq * 32;

    // ---- mask bias -> LDS (bf16: 0x0000 = 0.0, 0xFF80 = -inf) ----
    {
        const int* mb = mask + b * S_LEN;
        for (int i = t; i < S_LEN; i += 256)
            mbias[i] = mb[i] ? (u16)0 : (u16)0xFF80;
    }

    // ---- Q fragments (pre-scaled): B-layout col=ql, k = kd*16 + hb*8 + j ----
    bf16x8 qf[4];
    {
        const float* qp = q + baseq + (long)(qrow0 + ql) * D_K + hb * 8;
#pragma unroll
        for (int kd = 0; kd < 4; ++kd) qf[kd] = cvt8s(qp + kd * 16, scale2);
    }

    // ---- staging cursors: 4 global_load_lds per wave per tile; source pre-swizzled ----
    const int lrow = lane >> 3, lchk = lane & 7;
    const int rA = wq * 16 + lrow;
    const int rB = rA + 8;
    const short* ksA = kbf + baseq + (long)rA * D_K + ((lchk ^ (rA & 7)) * 8);
    const short* ksB = kbf + baseq + (long)rB * D_K + ((lchk ^ (rB & 7)) * 8);
    const short* vsA = vtb + ((long)bh * D_K + rA) * S_LEN + ((lchk ^ ((rA & 7) ^ ((rA >> 3) & 7))) * 8);
    const short* vsB = vtb + ((long)bh * D_K + rB) * S_LEN + ((lchk ^ ((rB & 7) ^ ((rB >> 3) & 7))) * 8);

    auto STAGE_K = [&](int sel) {            // sequential tiles: 0,1,2,...
        char* kdst = (char*)&kbuf[sel][0];
        gld16(ksA, kdst + (wq * 16) * 128);
        gld16(ksB, kdst + (wq * 16 + 8) * 128);
        ksA += KVB * D_K; ksB += KVB * D_K;
    };
    auto STAGE_V = [&](int sel) {            // sequential tiles: 0,1,2,...
        char* vdst = (char*)&vbuf[sel][0];
        gld16(vsA, vdst + (wq * 16) * 128);
        gld16(vsB, vdst + (wq * 16 + 8) * 128);
        vsA += KVB; vsB += KVB;
    };

    f32x16 o0, o1;
#pragma unroll
    for (int r = 0; r < 16; ++r) { o0[r] = 0.f; o1[r] = 0.f; }
    float lrun = 0.f;

    // st = logits of the CURRENT tile (computed one iteration ahead)
    f32x16 st0, st1;

    // QK for tile at kv0, K in kbuf[sel]; C-init = mask bias (bf16 -> f32 bit-expand)
    auto QK = [&](int kv0, int sel) {
        const char* kbp = (const char*)&kbuf[sel][0];
#pragma unroll
        for (int kb32 = 0; kb32 < 2; ++kb32) {
            f32x16 acc;
            {
                const u16* bp = &mbias[kv0 + kb32 * 32 + 4 * hb];
                uint2 g0 = *(const uint2*)(bp);        // keys +0..3
                uint2 g1 = *(const uint2*)(bp + 8);    // keys +8..11
                uint2 g2 = *(const uint2*)(bp + 16);   // keys +16..19
                uint2 g3 = *(const uint2*)(bp + 24);   // keys +24..27
                acc[0]  = blo(g0.x); acc[1]  = bhi(g0.x);
                acc[2]  = blo(g0.y); acc[3]  = bhi(g0.y);
                acc[4]  = blo(g1.x); acc[5]  = bhi(g1.x);
                acc[6]  = blo(g1.y); acc[7]  = bhi(g1.y);
                acc[8]  = blo(g2.x); acc[9]  = bhi(g2.x);
                acc[10] = blo(g2.y); acc[11] = bhi(g2.y);
                acc[12] = blo(g3.x); acc[13] = bhi(g3.x);
                acc[14] = blo(g3.y); acc[15] = bhi(g3.y);
            }
            int krow = kb32 * 32 + ql;
            int rb = krow * 128, sz = (krow & 7) << 4;
            __builtin_amdgcn_s_setprio(1);
#pragma unroll
            for (int kd = 0; kd < 4; ++kd) {
                bf16x8 kf = *(const bf16x8*)(kbp + ((rb + (kd * 16 + hb * 8) * 2) ^ sz));
                acc = __builtin_amdgcn_mfma_f32_32x32x16_bf16(kf, qf[kd], acc, 0, 0, 0);
            }
            __builtin_amdgcn_s_setprio(0);
            if (kb32 == 0) st0 = acc; else st1 = acc;
        }
    };

    // ---- prologue: K0,V0 -> slot0, K1 -> slot1; seed st = QK(0) ----
    STAGE_K(0);
    STAGE_V(0);
    STAGE_K(1);
    __syncthreads();          // drain: K0,V0,K1 + mbias visible
    QK(0, 0);
    __syncthreads();          // all waves done reading K slot0 (iter0 stages K2 there)

    for (int tt = 0; tt < NT; ++tt) {
        if (tt + 2 < NT) STAGE_K(tt & 1);          // K[tt+2] -> slot tt&1
        if (tt + 1 < NT) STAGE_V((tt + 1) & 1);    // V[tt+1] -> slot (tt+1)&1

        // ---- softmax(tile tt): P = exp2(st), pack bf16 pairs; st dies here ----
        u32 w[2][8];
        float rs0 = 0.f, rs1 = 0.f;
#pragma unroll
        for (int m = 0; m < 8; ++m) {
            float p0 = __builtin_amdgcn_exp2f(st0[2 * m]);
            float p1 = __builtin_amdgcn_exp2f(st0[2 * m + 1]);
            rs0 += p0; rs1 += p1;
            u32 r;
            asm("v_cvt_pk_bf16_f32 %0, %1, %2" : "=v"(r) : "v"(p0), "v"(p1));
            w[0][m] = r;
        }
#pragma unroll
        for (int m = 0; m < 8; ++m) {
            float p0 = __builtin_amdgcn_exp2f(st1[2 * m]);
            float p1 = __builtin_amdgcn_exp2f(st1[2 * m + 1]);
            rs0 += p0; rs1 += p1;
            u32 r;
            asm("v_cvt_pk_bf16_f32 %0, %1, %2" : "=v"(r) : "v"(p0), "v"(p1));
            w[1][m] = r;
        }
        float rs = rs0 + rs1;
        rs += __shfl_xor(rs, 32, 64);
        lrun += rs;

        // ---- QK(tt+1) into st (T15: its MFMAs overlap pack above / exp next iter) ----
        if (tt + 1 < NT) QK((tt + 1) * KVB, (tt + 1) & 1);

        // ---- PV(tt): A-frag via permlane32_swap, B = V^T b128 reads ----
        const char* vbp = (const char*)&vbuf[tt & 1][0];
#pragma unroll
        for (int kbi = 0; kbi < 4; ++kbi) {
            int c = kbi >> 1, a2 = (kbi & 1) * 4;
            u32 x0 = w[c][a2 + 0], y0 = w[c][a2 + 2];
            u32 x1 = w[c][a2 + 1], y1 = w[c][a2 + 3];
            asm("v_permlane32_swap_b32 %0, %1" : "+v"(x0), "+v"(y0));
            asm("v_permlane32_swap_b32 %0, %1" : "+v"(x1), "+v"(y1));
            u32x4 av = {x0, x1, y0, y1};       // j01, j23, j45, j67
            bf16x8 pa = __builtin_bit_cast(bf16x8, av);
            __builtin_amdgcn_s_setprio(1);
#pragma unroll
            for (int dn = 0; dn < 2; ++dn) {
                int d = dn * 32 + ql;
                bf16x8 vf = *(const bf16x8*)(vbp +
                              ((d * 128 + (kbi * 16 + hb * 8) * 2) ^ vswz(d)));
                if (dn == 0)
                    o0 = __builtin_amdgcn_mfma_f32_32x32x16_bf16(pa, vf, o0, 0, 0, 0);
                else
                    o1 = __builtin_amdgcn_mfma_f32_32x32x16_bf16(pa, vf, o1, 0, 0, 0);
            }
            __builtin_amdgcn_s_setprio(0);
        }

        __syncthreads();   // drains vmcnt(0): stages issued this iter are in LDS
    }

    // ---- epilogue: out[qrow][d] = o / l ----
    float rl = 1.0f / lrun;
#pragma unroll
    for (int r = 0; r < 16; ++r) {
        int   cr  = (r & 3) + 8 * (r >> 2) + 4 * hb;
        float rlr = __shfl(rl, cr, 64);
        long  rowb = baseq + (long)(qrow0 + cr) * D_K;
        out[rowb + ql]      = o0[r] * rlr;
        out[rowb + 32 + ql] = o1[r] * rlr;
    }
}

// ---------------- fallback (round-3 kernel) if ws too small ----------------
__global__ __launch_bounds__(256)
void attn_fwd_legacy(const float* __restrict__ q, const float* __restrict__ k,
                     const float* __restrict__ v, const int* __restrict__ mask,
                     float* __restrict__ out) {
    const int id      = blockIdx.x;
    const int logical = (id & 7) * 128 + (id >> 3);
    const int bh      = logical >> 4;
    const int qblk    = logical & 15;
    const int b       = bh >> 4;
    const int t       = threadIdx.x;
    const int lane    = t & 63;
    const int wq      = t >> 6;
    const int hb      = lane >> 5;
    const int ql      = lane & 31;

    __shared__ __align__(16) short kbuf[KVB * D_K];
    __shared__ __align__(16) short vtbuf[D_K * KVB];
    __shared__ float mbias[S_LEN];

    const float scale2 = 0.125f * 1.44269504f;
    const long  base   = (long)bh * S_LEN * D_K;
    const int   qrow0  = qblk * QPB + wq * 32;

    {
        const int* mb = mask + b * S_LEN;
        for (int i = t; i < S_LEN; i += 256)
            mbias[i] = mb[i] ? 0.f : -1.442695e9f;
    }

    bf16x8 qf[4];
    {
        const float* qp = q + base + (long)(qrow0 + ql) * D_K + hb * 8;
#pragma unroll
        for (int kd = 0; kd < 4; ++kd) qf[kd] = cvt8s(qp + kd * 16, 1.0f);
    }

    f32x16 o0, o1;
#pragma unroll
    for (int r = 0; r < 16; ++r) { o0[r] = 0.f; o1[r] = 0.f; }
    float mrun = -1e30f, lrun = 0.f;

    const int srow = t >> 3;
    const int scol = t & 7;
    float4 kr[2][2], vr[2][2];

    auto LOADT = [&](int kv0) {
#pragma unroll
        for (int u2 = 0; u2 < 2; ++u2) {
            int row = srow + u2 * 32;
            const float* kp = k + base + (long)(kv0 + row) * D_K + scol * 8;
            const float* vp = v + base + (long)(kv0 + row) * D_K + scol * 8;
            kr[u2][0] = *(const float4*)kp; kr[u2][1] = *(const float4*)(kp + 4);
            vr[u2][0] = *(const float4*)vp; vr[u2][1] = *(const float4*)(vp + 4);
        }
    };

    LOADT(0);

    for (int tt = 0; tt < NT; ++tt) {
        const int kv0 = tt * KVB;
        __syncthreads();
#pragma unroll
        for (int u2 = 0; u2 < 2; ++u2) {
            int row = srow + u2 * 32;
            bf16x8 fk, fv;
#pragma unroll
            for (int j = 0; j < 4; ++j) {
                fk[j]     = f2bfs(((const float*)&kr[u2][0])[j]);
                fk[j + 4] = f2bfs(((const float*)&kr[u2][1])[j]);
                fv[j]     = f2bfs(((const float*)&vr[u2][0])[j]);
                fv[j + 4] = f2bfs(((const float*)&vr[u2][1])[j]);
            }
            int kbyte = (row * 128 + scol * 16) ^ ((row & 7) << 4);
            *(bf16x8*)((char*)kbuf + kbyte) = fk;
#pragma unroll
            for (int j = 0; j < 8; ++j) {
                int d = scol * 8 + j;
                *(short*)((char*)vtbuf + ((d * 128 + row * 2) ^ vswz(d))) = fv[j];
            }
        }
        if (tt + 1 < NT) LOADT(kv0 + KVB);
        __syncthreads();

        f32x16 stl[2];
#pragma unroll
        for (int kb32 = 0; kb32 < 2; ++kb32) {
            f32x16 acc;
#pragma unroll
            for (int r = 0; r < 16; ++r) acc[r] = 0.f;
            int krow = kb32 * 32 + ql;
            int rb = krow * 128, sz = (krow & 7) << 4;
#pragma unroll
            for (int kd = 0; kd < 4; ++kd) {
                bf16x8 kf = *(const bf16x8*)((const char*)kbuf + ((rb + (kd * 16 + hb * 8) * 2) ^ sz));
                acc = __builtin_amdgcn_mfma_f32_32x32x16_bf16(kf, qf[kd], acc, 0, 0, 0);
            }
            stl[kb32] = acc;
        }
#pragma unroll
        for (int kb32 = 0; kb32 < 2; ++kb32)
#pragma unroll
            for (int r = 0; r < 16; ++r) {
                int key = kv0 + kb32 * 32 + (r & 3) + 8 * (r >> 2) + 4 * hb;
                stl[kb32][r] = fmaf(stl[kb32][r], scale2, mbias[key]);
            }

        float m8[8];
#pragma unroll
        for (int i = 0; i < 8; ++i)
            m8[i] = fmaxf(fmaxf(stl[0][i], stl[0][i + 8]),
                          fmaxf(stl[1][i], stl[1][i + 8]));
        float tmax = fmaxf(fmaxf(fmaxf(m8[0], m8[1]), fmaxf(m8[2], m8[3])),
                           fmaxf(fmaxf(m8[4], m8[5]), fmaxf(m8[6], m8[7])));
        tmax = fmaxf(tmax, __shfl_xor(tmax, 32, 64));

        if (__any(tmax > mrun + 10.0f)) {
            float mnew = fmaxf(mrun, tmax);
            float al   = __builtin_amdgcn_exp2f(mrun - mnew);
            mrun = mnew;
            lrun *= al;
#pragma unroll
            for (int r = 0; r < 16; ++r) {
                float ar = __shfl(al, (r & 3) + 8 * (r >> 2) + 4 * hb, 64);
                o0[r] *= ar; o1[r] *= ar;
            }
        }

        u32 w[2][8];
        float rs = 0.f;
#pragma unroll
        for (int kb32 = 0; kb32 < 2; ++kb32)
#pragma unroll
            for (int m = 0; m < 8; ++m) {
                float p0 = __builtin_amdgcn_exp2f(stl[kb32][2 * m]     - mrun);
                float p1 = __builtin_amdgcn_exp2f(stl[kb32][2 * m + 1] - mrun);
                rs += p0 + p1;
                w[kb32][m] = (u32)(unsigned short)f2bfs(p0) |
                             ((u32)(unsigned short)f2bfs(p1) << 16);
            }
        rs += __shfl_xor(rs, 32, 64);
        lrun += rs;

#pragma unroll
        for (int kbi = 0; kbi < 4; ++kbi) {
            int c = kbi >> 1, a2 = (kbi & 1) * 4;
            u32 x0 = w[c][a2 + 0], y0 = w[c][a2 + 2];
            u32 x1 = w[c][a2 + 1], y1 = w[c][a2 + 3];
            asm("v_permlane32_swap_b32 %0, %1" : "+v"(x0), "+v"(y0));
            asm("v_permlane32_swap_b32 %0, %1" : "+v"(x1), "+v"(y1));
            u32x4 av = {x0, x1, y0, y1};
            bf16x8 pa = __builtin_bit_cast(bf16x8, av);
#pragma unroll
            for (int dn = 0; dn < 2; ++dn) {
                int d = dn * 32 + ql;
                bf16x8 vf = *(const bf16x8*)((const char*)vtbuf +
                              ((d * 128 + (kbi * 16 + hb * 8) * 2) ^ vswz(d)));
                if (dn == 0)
                    o0 = __builtin_amdgcn_mfma_f32_32x32x16_bf16(pa, vf, o0, 0, 0, 0);
                else
                    o1 = __builtin_amdgcn_mfma_f32_32x32x16_bf16(pa, vf, o1, 0, 0, 0);
            }
        }
    }

    float rl = 1.0f / lrun;
#pragma unroll
    for (int r = 0; r < 16; ++r) {
        int   cr  = (r & 3) + 8 * (r >> 2) + 4 * hb;
        float rlr = __shfl(rl, cr, 64);
        long  rowb = base + (long)(qrow0 + cr) * D_K;
        out[rowb + ql]      = o0[r] * rlr;
        out[rowb + 32 + ql] = o1[r] * rlr;
    }
}

extern "C" void kernel_launch(void* const* d_in, const int* in_sizes, int n_in,
                              void* d_out, int out_size, void* d_ws, size_t ws_size,
                              hipStream_t stream) {
    const float* q    = (const float*)d_in[0];
    const float* k    = (const float*)d_in[1];
    const float* v    = (const float*)d_in[2];
    const int*   mask = (const int*)d_in[3];
    float*       out  = (float*)d_out;

    if (ws_size >= (size_t)WS_NEED) {
        short* kbf = (short*)d_ws;
        short* vtb = kbf + (long)N_B * N_H * S_LEN * D_K;
        cvt_kv<<<dim3(N_B * N_H * (S_LEN / 64)), 256, 0, stream>>>(k, v, kbf, vtb);
        attn_fwd<<<dim3(NQB * N_B * N_H), 256, 0, stream>>>(q, kbf, vtb, mask, out);
    } else {
        attn_fwd_legacy<<<dim3(NQB * N_B * N_H), 256, 0, stream>>>(q, k, v, mask, out);
    }
}

// Round 9
// 82.774 us; speedup vs baseline: 1.4149x; 1.4149x over previous
//
#include <hip/hip_runtime.h>
#include <hip/hip_bf16.h>

#define S_LEN 2048
#define D_K   64
#define N_H   16
#define N_B   4
#define KVB   64
#define QPB   128                 // q-rows per block (4 waves x 32)
#define NQB   (S_LEN / QPB)       // 16
#define NBH   (N_B * N_H)
// ws: K_compact + V^T_compact (bf16, full-size padded) + idx + cnt
#define WS_NEED (2L * NBH * S_LEN * D_K * 2 + 4L * S_LEN * 4 + 16)

typedef __attribute__((ext_vector_type(8)))  short bf16x8;
typedef __attribute__((ext_vector_type(16))) float f32x16;
typedef unsigned int u32;
typedef __attribute__((ext_vector_type(4))) u32 u32x4;

__device__ inline short f2bfs(float x) {
    __hip_bfloat16 h = __float2bfloat16(x);
    return __builtin_bit_cast(short, h);
}

__device__ inline bf16x8 cvt8(const float* __restrict__ p) {
    float4 a = *(const float4*)p;
    float4 b = *(const float4*)(p + 4);
    bf16x8 f;
    f[0] = f2bfs(a.x); f[1] = f2bfs(a.y);
    f[2] = f2bfs(a.z); f[3] = f2bfs(a.w);
    f[4] = f2bfs(b.x); f[5] = f2bfs(b.y);
    f[6] = f2bfs(b.z); f[7] = f2bfs(b.w);
    return f;
}

__device__ inline bf16x8 cvt8s(const float* __restrict__ p, float s) {
    float4 a = *(const float4*)p;
    float4 b = *(const float4*)(p + 4);
    bf16x8 f;
    f[0] = f2bfs(a.x * s); f[1] = f2bfs(a.y * s);
    f[2] = f2bfs(a.z * s); f[3] = f2bfs(a.w * s);
    f[4] = f2bfs(b.x * s); f[5] = f2bfs(b.y * s);
    f[6] = f2bfs(b.z * s); f[7] = f2bfs(b.w * s);
    return f;
}

// V^T swizzle: spreads row-d b128 reads across banks
__device__ inline int vswz(int d) { return ((d & 7) ^ ((d >> 3) & 7)) << 4; }

__device__ inline void gld16(const void* g, void* l) {
    __builtin_amdgcn_global_load_lds(
        (const __attribute__((address_space(1))) void*)g,
        (__attribute__((address_space(3))) void*)l, 16, 0, 0);
}

// ---------------- pass A: stable compaction of unmasked key indices ----------------
__global__ __launch_bounds__(64)
void mask_scan(const int* __restrict__ mask, int* __restrict__ idx,
               int* __restrict__ cnt) {
    const int b = blockIdx.x, lane = threadIdx.x;
    const int* mb = mask + b * S_LEN;
    int base = 0;
    for (int j0 = 0; j0 < S_LEN; j0 += 64) {
        int mv = mb[j0 + lane];
        unsigned long long ball = __ballot(mv != 0);
        int pos = base + __popcll(ball & ((1ull << lane) - 1ull));
        if (mv) idx[b * S_LEN + pos] = j0 + lane;
        base += __popcll(ball);
    }
    if (lane == 0) cnt[b] = base;
}

// ---------------- pass B: gather+convert K -> bf16 compact, V -> bf16^T compact ----------------
__global__ __launch_bounds__(256)
void gather_cvt(const float* __restrict__ k, const float* __restrict__ v,
                const int* __restrict__ idx, const int* __restrict__ cnt,
                short* __restrict__ kc, short* __restrict__ vt) {
    const int bid = blockIdx.x, bh = bid >> 5, i0 = (bid & 31) * 64;
    const int b = bh >> 4;
    const int m = cnt[b];
    if (i0 >= ((m + 63) & ~63)) return;      // uniform: tile beyond padded region
    const int t = threadIdx.x;
    const int r = t >> 2, c0 = (t & 3) * 16;
    const int i = i0 + r;

    __shared__ __align__(16) short tile_[64][72];
    bf16x8 fv0, fv1, fk0, fk1;
    if (i < m) {
        const int src = idx[b * S_LEN + i];
        const float* kp = k + ((long)bh * S_LEN + src) * D_K + c0;
        const float* vp = v + ((long)bh * S_LEN + src) * D_K + c0;
        fk0 = cvt8(kp); fk1 = cvt8(kp + 8);
        fv0 = cvt8(vp); fv1 = cvt8(vp + 8);
    } else {
#pragma unroll
        for (int j = 0; j < 8; ++j) { fk0[j] = 0; fk1[j] = 0; fv0[j] = 0; fv1[j] = 0; }
    }
    // K compact (row-major [bh][i][d])
    short* kdst = kc + ((long)bh * S_LEN + i) * D_K + c0;
    *(bf16x8*)kdst       = fk0;
    *(bf16x8*)(kdst + 8) = fk1;
    // V transpose via padded LDS -> [bh][d][i]
    *(bf16x8*)&tile_[r][c0]     = fv0;
    *(bf16x8*)&tile_[r][c0 + 8] = fv1;
    __syncthreads();
    const int dd = t >> 2, k0 = (t & 3) * 16;
    bf16x8 h0, h1;
#pragma unroll
    for (int j = 0; j < 8; ++j) {
        h0[j] = tile_[k0 + j][dd];
        h1[j] = tile_[k0 + 8 + j][dd];
    }
    short* dst = vt + ((long)bh * D_K + dd) * S_LEN + i0 + k0;
    *(bf16x8*)dst       = h0;
    *(bf16x8*)(dst + 8) = h1;
}

// ---------------- main attention kernel (compacted bf16 K / V^T) ----------------
__global__ __launch_bounds__(256)
void attn_fwd(const float* __restrict__ q, const short* __restrict__ kbf,
              const short* __restrict__ vtb, const int* __restrict__ cnt,
              float* __restrict__ out) {
    // XCD-aware bijective swizzle (1024 = 8*128)
    const int id      = blockIdx.x;
    const int logical = (id & 7) * 128 + (id >> 3);
    const int bh      = logical >> 4;
    const int qblk    = logical & 15;
    const int b       = bh >> 4;
    const int t       = threadIdx.x;
    const int lane    = t & 63;
    const int wq      = t >> 6;
    const int hb      = lane >> 5;
    const int ql      = lane & 31;

    const int m   = cnt[b];                   // unmasked key count for this batch
    const int NTr = (m + 63) >> 6;            // tiles to process

    // LDS = 16K (K dbuf) + 16K (V dbuf) = 32 KB
    __shared__ __align__(16) short kbuf[2][KVB * D_K];   // [key][d], XOR (row&7)<<4
    __shared__ __align__(16) short vbuf[2][D_K * KVB];   // [d][key], XOR vswz(d)

    const float scale2 = 0.125f * 1.44269504f;           // 1/sqrt(64)*log2(e)
    const long  baseq  = (long)bh * S_LEN * D_K;
    const int   qrow0  = qblk * QPB + wq * 32;

    // ---- Q fragments (pre-scaled): B-layout col=ql, k = kd*16 + hb*8 + j ----
    bf16x8 qf[4];
    {
        const float* qp = q + baseq + (long)(qrow0 + ql) * D_K + hb * 8;
#pragma unroll
        for (int kd = 0; kd < 4; ++kd) qf[kd] = cvt8s(qp + kd * 16, scale2);
    }

    // ---- staging cursors: 4 global_load_lds per wave per tile; source pre-swizzled ----
    const int lrow = lane >> 3, lchk = lane & 7;
    const int rA = wq * 16 + lrow;
    const int rB = rA + 8;
    const short* ksA = kbf + baseq + (long)rA * D_K + ((lchk ^ (rA & 7)) * 8);
    const short* ksB = kbf + baseq + (long)rB * D_K + ((lchk ^ (rB & 7)) * 8);
    const short* vsA = vtb + ((long)bh * D_K + rA) * S_LEN + ((lchk ^ ((rA & 7) ^ ((rA >> 3) & 7))) * 8);
    const short* vsB = vtb + ((long)bh * D_K + rB) * S_LEN + ((lchk ^ ((rB & 7) ^ ((rB >> 3) & 7))) * 8);

    auto STAGE_K = [&](int sel) {            // sequential tiles: 0,1,2,...
        char* kdst = (char*)&kbuf[sel][0];
        gld16(ksA, kdst + (wq * 16) * 128);
        gld16(ksB, kdst + (wq * 16 + 8) * 128);
        ksA += KVB * D_K; ksB += KVB * D_K;
    };
    auto STAGE_V = [&](int sel) {            // sequential tiles: 0,1,2,...
        char* vdst = (char*)&vbuf[sel][0];
        gld16(vsA, vdst + (wq * 16) * 128);
        gld16(vsB, vdst + (wq * 16 + 8) * 128);
        vsA += KVB; vsB += KVB;
    };

    f32x16 o0, o1;
#pragma unroll
    for (int r = 0; r < 16; ++r) { o0[r] = 0.f; o1[r] = 0.f; }
    float lrun = 0.f;

    // st = logits of the CURRENT tile (computed one iteration ahead)
    f32x16 st0, st1;

    // QK for tile at kv0, K in kbuf[sel]; C-init 0 (all kept keys unmasked);
    // last tile: -1e9 on zero-padded keys (key >= m)
    auto QK = [&](int kv0, int sel, bool lastt) {
        const char* kbp = (const char*)&kbuf[sel][0];
#pragma unroll
        for (int kb32 = 0; kb32 < 2; ++kb32) {
            f32x16 acc;
            if (!lastt) {
#pragma unroll
                for (int r = 0; r < 16; ++r) acc[r] = 0.f;
            } else {
                int keyb = kv0 + kb32 * 32 + 4 * hb;
#pragma unroll
                for (int r = 0; r < 16; ++r) {
                    int key = keyb + (r & 3) + 8 * (r >> 2);
                    acc[r] = (key < m) ? 0.f : -1e9f;
                }
            }
            int krow = kb32 * 32 + ql;
            int rb = krow * 128, sz = (krow & 7) << 4;
            __builtin_amdgcn_s_setprio(1);
#pragma unroll
            for (int kd = 0; kd < 4; ++kd) {
                bf16x8 kf = *(const bf16x8*)(kbp + ((rb + (kd * 16 + hb * 8) * 2) ^ sz));
                acc = __builtin_amdgcn_mfma_f32_32x32x16_bf16(kf, qf[kd], acc, 0, 0, 0);
            }
            __builtin_amdgcn_s_setprio(0);
            if (kb32 == 0) st0 = acc; else st1 = acc;
        }
    };

    // ---- prologue: K0,V0 -> slot0, K1 -> slot1; seed st = QK(0) ----
    STAGE_K(0);
    STAGE_V(0);
    if (NTr > 1) STAGE_K(1);
    __syncthreads();          // drain: K0,V0,(K1) visible
    QK(0, 0, NTr == 1);
    __syncthreads();          // all waves done reading K slot0 (iter0 stages K2 there)

    for (int tt = 0; tt < NTr; ++tt) {
        if (tt + 2 < NTr) STAGE_K(tt & 1);          // K[tt+2] -> slot tt&1
        if (tt + 1 < NTr) STAGE_V((tt + 1) & 1);    // V[tt+1] -> slot (tt+1)&1

        // ---- softmax(tile tt): P = exp2(st), pack bf16 pairs; st dies here ----
        u32 w[2][8];
        float rs0 = 0.f, rs1 = 0.f;
#pragma unroll
        for (int mm = 0; mm < 8; ++mm) {
            float p0 = __builtin_amdgcn_exp2f(st0[2 * mm]);
            float p1 = __builtin_amdgcn_exp2f(st0[2 * mm + 1]);
            rs0 += p0; rs1 += p1;
            u32 r;
            asm("v_cvt_pk_bf16_f32 %0, %1, %2" : "=v"(r) : "v"(p0), "v"(p1));
            w[0][mm] = r;
        }
#pragma unroll
        for (int mm = 0; mm < 8; ++mm) {
            float p0 = __builtin_amdgcn_exp2f(st1[2 * mm]);
            float p1 = __builtin_amdgcn_exp2f(st1[2 * mm + 1]);
            rs0 += p0; rs1 += p1;
            u32 r;
            asm("v_cvt_pk_bf16_f32 %0, %1, %2" : "=v"(r) : "v"(p0), "v"(p1));
            w[1][mm] = r;
        }
        float rs = rs0 + rs1;
        rs += __shfl_xor(rs, 32, 64);
        lrun += rs;

        // ---- QK(tt+1) into st (T15: its MFMAs overlap pack above / exp next iter) ----
        if (tt + 1 < NTr) QK((tt + 1) * KVB, (tt + 1) & 1, tt + 2 == NTr);

        // ---- PV(tt): A-frag via permlane32_swap, B = V^T b128 reads ----
        const char* vbp = (const char*)&vbuf[tt & 1][0];
#pragma unroll
        for (int kbi = 0; kbi < 4; ++kbi) {
            int c = kbi >> 1, a2 = (kbi & 1) * 4;
            u32 x0 = w[c][a2 + 0], y0 = w[c][a2 + 2];
            u32 x1 = w[c][a2 + 1], y1 = w[c][a2 + 3];
            asm("v_permlane32_swap_b32 %0, %1" : "+v"(x0), "+v"(y0));
            asm("v_permlane32_swap_b32 %0, %1" : "+v"(x1), "+v"(y1));
            u32x4 av = {x0, x1, y0, y1};       // j01, j23, j45, j67
            bf16x8 pa = __builtin_bit_cast(bf16x8, av);
            __builtin_amdgcn_s_setprio(1);
#pragma unroll
            for (int dn = 0; dn < 2; ++dn) {
                int d = dn * 32 + ql;
                bf16x8 vf = *(const bf16x8*)(vbp +
                              ((d * 128 + (kbi * 16 + hb * 8) * 2) ^ vswz(d)));
                if (dn == 0)
                    o0 = __builtin_amdgcn_mfma_f32_32x32x16_bf16(pa, vf, o0, 0, 0, 0);
                else
                    o1 = __builtin_amdgcn_mfma_f32_32x32x16_bf16(pa, vf, o1, 0, 0, 0);
            }
            __builtin_amdgcn_s_setprio(0);
        }

        __syncthreads();   // drains vmcnt(0): stages issued this iter are in LDS
    }

    // ---- epilogue: out[qrow][d] = o / l ----
    float rl = 1.0f / lrun;
#pragma unroll
    for (int r = 0; r < 16; ++r) {
        int   cr  = (r & 3) + 8 * (r >> 2) + 4 * hb;
        float rlr = __shfl(rl, cr, 64);
        long  rowb = baseq + (long)(qrow0 + cr) * D_K;
        out[rowb + ql]      = o0[r] * rlr;
        out[rowb + 32 + ql] = o1[r] * rlr;
    }
}

// ---------------- fallback (round-3 kernel, no compaction) if ws too small ----------------
__global__ __launch_bounds__(256)
void attn_fwd_legacy(const float* __restrict__ q, const float* __restrict__ k,
                     const float* __restrict__ v, const int* __restrict__ mask,
                     float* __restrict__ out) {
    const int id      = blockIdx.x;
    const int logical = (id & 7) * 128 + (id >> 3);
    const int bh      = logical >> 4;
    const int qblk    = logical & 15;
    const int b       = bh >> 4;
    const int t       = threadIdx.x;
    const int lane    = t & 63;
    const int wq      = t >> 6;
    const int hb      = lane >> 5;
    const int ql      = lane & 31;

    __shared__ __align__(16) short kbuf[KVB * D_K];
    __shared__ __align__(16) short vtbuf[D_K * KVB];
    __shared__ float mbias[S_LEN];

    const float scale2 = 0.125f * 1.44269504f;
    const long  base   = (long)bh * S_LEN * D_K;
    const int   qrow0  = qblk * QPB + wq * 32;

    {
        const int* mb = mask + b * S_LEN;
        for (int i = t; i < S_LEN; i += 256)
            mbias[i] = mb[i] ? 0.f : -1.442695e9f;
    }

    bf16x8 qf[4];
    {
        const float* qp = q + base + (long)(qrow0 + ql) * D_K + hb * 8;
#pragma unroll
        for (int kd = 0; kd < 4; ++kd) qf[kd] = cvt8s(qp + kd * 16, 1.0f);
    }

    f32x16 o0, o1;
#pragma unroll
    for (int r = 0; r < 16; ++r) { o0[r] = 0.f; o1[r] = 0.f; }
    float mrun = -1e30f, lrun = 0.f;

    const int srow = t >> 3;
    const int scol = t & 7;
    float4 kr[2][2], vr[2][2];

    auto LOADT = [&](int kv0) {
#pragma unroll
        for (int u2 = 0; u2 < 2; ++u2) {
            int row = srow + u2 * 32;
            const float* kp = k + base + (long)(kv0 + row) * D_K + scol * 8;
            const float* vp = v + base + (long)(kv0 + row) * D_K + scol * 8;
            kr[u2][0] = *(const float4*)kp; kr[u2][1] = *(const float4*)(kp + 4);
            vr[u2][0] = *(const float4*)vp; vr[u2][1] = *(const float4*)(vp + 4);
        }
    };

    LOADT(0);

    for (int tt = 0; tt < S_LEN / KVB; ++tt) {
        const int kv0 = tt * KVB;
        __syncthreads();
#pragma unroll
        for (int u2 = 0; u2 < 2; ++u2) {
            int row = srow + u2 * 32;
            bf16x8 fk, fv;
#pragma unroll
            for (int j = 0; j < 4; ++j) {
                fk[j]     = f2bfs(((const float*)&kr[u2][0])[j]);
                fk[j + 4] = f2bfs(((const float*)&kr[u2][1])[j]);
                fv[j]     = f2bfs(((const float*)&vr[u2][0])[j]);
                fv[j + 4] = f2bfs(((const float*)&vr[u2][1])[j]);
            }
            int kbyte = (row * 128 + scol * 16) ^ ((row & 7) << 4);
            *(bf16x8*)((char*)kbuf + kbyte) = fk;
#pragma unroll
            for (int j = 0; j < 8; ++j) {
                int d = scol * 8 + j;
                *(short*)((char*)vtbuf + ((d * 128 + row * 2) ^ vswz(d))) = fv[j];
            }
        }
        if (tt + 1 < S_LEN / KVB) LOADT(kv0 + KVB);
        __syncthreads();

        f32x16 stl[2];
#pragma unroll
        for (int kb32 = 0; kb32 < 2; ++kb32) {
            f32x16 acc;
#pragma unroll
            for (int r = 0; r < 16; ++r) acc[r] = 0.f;
            int krow = kb32 * 32 + ql;
            int rb = krow * 128, sz = (krow & 7) << 4;
#pragma unroll
            for (int kd = 0; kd < 4; ++kd) {
                bf16x8 kf = *(const bf16x8*)((const char*)kbuf + ((rb + (kd * 16 + hb * 8) * 2) ^ sz));
                acc = __builtin_amdgcn_mfma_f32_32x32x16_bf16(kf, qf[kd], acc, 0, 0, 0);
            }
            stl[kb32] = acc;
        }
#pragma unroll
        for (int kb32 = 0; kb32 < 2; ++kb32)
#pragma unroll
            for (int r = 0; r < 16; ++r) {
                int key = kv0 + kb32 * 32 + (r & 3) + 8 * (r >> 2) + 4 * hb;
                stl[kb32][r] = fmaf(stl[kb32][r], scale2, mbias[key]);
            }

        float m8[8];
#pragma unroll
        for (int i = 0; i < 8; ++i)
            m8[i] = fmaxf(fmaxf(stl[0][i], stl[0][i + 8]),
                          fmaxf(stl[1][i], stl[1][i + 8]));
        float tmax = fmaxf(fmaxf(fmaxf(m8[0], m8[1]), fmaxf(m8[2], m8[3])),
                           fmaxf(fmaxf(m8[4], m8[5]), fmaxf(m8[6], m8[7])));
        tmax = fmaxf(tmax, __shfl_xor(tmax, 32, 64));

        if (__any(tmax > mrun + 10.0f)) {
            float mnew = fmaxf(mrun, tmax);
            float al   = __builtin_amdgcn_exp2f(mrun - mnew);
            mrun = mnew;
            lrun *= al;
#pragma unroll
            for (int r = 0; r < 16; ++r) {
                float ar = __shfl(al, (r & 3) + 8 * (r >> 2) + 4 * hb, 64);
                o0[r] *= ar; o1[r] *= ar;
            }
        }

        u32 w[2][8];
        float rs = 0.f;
#pragma unroll
        for (int kb32 = 0; kb32 < 2; ++kb32)
#pragma unroll
            for (int mm = 0; mm < 8; ++mm) {
                float p0 = __builtin_amdgcn_exp2f(stl[kb32][2 * mm]     - mrun);
                float p1 = __builtin_amdgcn_exp2f(stl[kb32][2 * mm + 1] - mrun);
                rs += p0 + p1;
                w[kb32][mm] = (u32)(unsigned short)f2bfs(p0) |
                              ((u32)(unsigned short)f2bfs(p1) << 16);
            }
        rs += __shfl_xor(rs, 32, 64);
        lrun += rs;

#pragma unroll
        for (int kbi = 0; kbi < 4; ++kbi) {
            int c = kbi >> 1, a2 = (kbi & 1) * 4;
            u32 x0 = w[c][a2 + 0], y0 = w[c][a2 + 2];
            u32 x1 = w[c][a2 + 1], y1 = w[c][a2 + 3];
            asm("v_permlane32_swap_b32 %0, %1" : "+v"(x0), "+v"(y0));
            asm("v_permlane32_swap_b32 %0, %1" : "+v"(x1), "+v"(y1));
            u32x4 av = {x0, x1, y0, y1};
            bf16x8 pa = __builtin_bit_cast(bf16x8, av);
#pragma unroll
            for (int dn = 0; dn < 2; ++dn) {
                int d = dn * 32 + ql;
                bf16x8 vf = *(const bf16x8*)((const char*)vtbuf +
                              ((d * 128 + (kbi * 16 + hb * 8) * 2) ^ vswz(d)));
                if (dn == 0)
                    o0 = __builtin_amdgcn_mfma_f32_32x32x16_bf16(pa, vf, o0, 0, 0, 0);
                else
                    o1 = __builtin_amdgcn_mfma_f32_32x32x16_bf16(pa, vf, o1, 0, 0, 0);
            }
        }
    }

    float rl = 1.0f / lrun;
#pragma unroll
    for (int r = 0; r < 16; ++r) {
        int   cr  = (r & 3) + 8 * (r >> 2) + 4 * hb;
        float rlr = __shfl(rl, cr, 64);
        long  rowb = base + (long)(qrow0 + cr) * D_K;
        out[rowb + ql]      = o0[r] * rlr;
        out[rowb + 32 + ql] = o1[r] * rlr;
    }
}

extern "C" void kernel_launch(void* const* d_in, const int* in_sizes, int n_in,
                              void* d_out, int out_size, void* d_ws, size_t ws_size,
                              hipStream_t stream) {
    const float* q    = (const float*)d_in[0];
    const float* k    = (const float*)d_in[1];
    const float* v    = (const float*)d_in[2];
    const int*   mask = (const int*)d_in[3];
    float*       out  = (float*)d_out;

    if (ws_size >= (size_t)WS_NEED) {
        short* kc  = (short*)d_ws;
        short* vt  = kc + (long)NBH * S_LEN * D_K;
        int*   idx = (int*)(vt + (long)NBH * S_LEN * D_K);
        int*   cnt = idx + 4 * S_LEN;
        mask_scan<<<dim3(N_B), 64, 0, stream>>>(mask, idx, cnt);
        gather_cvt<<<dim3(NBH * (S_LEN / 64)), 256, 0, stream>>>(k, v, idx, cnt, kc, vt);
        attn_fwd<<<dim3(NQB * NBH), 256, 0, stream>>>(q, kc, vt, cnt, out);
    } else {
        attn_fwd_legacy<<<dim3(NQB * NBH), 256, 0, stream>>>(q, k, v, mask, out);
    }
}